// Round 5
// baseline (334.180 us; speedup 1.0000x reference)
//
#include <hip/hip_runtime.h>

#define DI __device__ __forceinline__

constexpr int Bc = 4, Tc = 4096, Ic = 1024, Ec = 16, Kc = 512, Jc = 1024;

typedef __attribute__((ext_vector_type(8))) short short8;
typedef __attribute__((ext_vector_type(4))) float floatx4;

// pack two fp32 -> two bf16 (round-half-up): low16 = bf16(a), high16 = bf16(b)
DI unsigned pack2_bf16(float a, float b) {
  union { float f; unsigned u; } ua, ub;
  ua.f = a; ub.f = b;
  const unsigned x = ua.u + 0x8000u;
  const unsigned y = ub.u + 0x8000u;
#if __has_builtin(__builtin_amdgcn_perm)
  return __builtin_amdgcn_perm(y, x, 0x07060302u);
#else
  return (x >> 16) | (y & 0xFFFF0000u);
#endif
}

DI void async_load16(const void* g, void* lds) {
  __builtin_amdgcn_global_load_lds((const __attribute__((address_space(1))) void*)g,
                                   (__attribute__((address_space(3))) void*)lds,
                                   16, 0, 0);
}

// ---------------------------------------------------------------------------
// prep v4. Even blocks: X gather+cast into ROW-MAJOR Xg[32768][1024] bf16
//   (coalesced both sides, no LDS, no sync — proven in v3).
// Odd blocks: W transpose+cast via LDS tile (R0 structure: 6 VMEM instrs per
//   thread at >=512B/instr, vs v3's 36 scalar loads — prep was VMEM-issue
//   bound, not BW bound). Wt layout unchanged: [(e*8+jt)*32+kk][128n][32i].
__global__ __launch_bounds__(256) void prep(const float* __restrict__ X,
                                            const int* __restrict__ ind,
                                            const float* __restrict__ W,
                                            unsigned short* __restrict__ Xg,
                                            unsigned short* __restrict__ Wt) {
  __shared__ __align__(16) float wtile[32][129];  // 16.5 KB (odd blocks only)
  const int bid = blockIdx.x >> 1;
  const int t = threadIdx.x;

  if ((blockIdx.x & 1) == 0) {
    // ---- X part: 32768 rows x 32 chunks; 8 rows per block, 4096 blocks ----
    const int r8 = t >> 5;              // row within block
    const int c  = t & 31;              // 32-float chunk within row
    const int R  = bid * 8 + r8;        // gathered-row id
    const int b  = R >> 13;             // E*K = 8192 rows per batch
    const int xr = ind[R];
    const float* src = X + ((size_t)(b * Tc + xr)) * Ic + c * 32;
    unsigned u[16];
#pragma unroll
    for (int q = 0; q < 8; ++q) {
      const float4 v = *(const float4*)(src + q * 4);
      u[2 * q]     = pack2_bf16(v.x, v.y);
      u[2 * q + 1] = pack2_bf16(v.z, v.w);
    }
    unsigned short* dst = Xg + (size_t)R * Ic + c * 32;
#pragma unroll
    for (int q = 0; q < 4; ++q) *(uint4*)(dst + q * 8) = *(uint4*)&u[4 * q];
  } else {
    // ---- W part: e(16) x jt(8) x kk(32) = 4096 blocks, LDS transpose ----
    const int kk = bid & 31;
    const int jt = (bid >> 5) & 7;
    const int e  = bid >> 8;
    const float* Wp = W + ((size_t)(e * Ic + kk * 32)) * Jc + jt * 128;
#pragma unroll
    for (int p = 0; p < 4; ++p) {
      const int il = p * 8 + (t >> 5);
      const int c4 = (t & 31) * 4;
      const float4 v = *(const float4*)(Wp + (size_t)il * Jc + c4);
      wtile[il][c4 + 0] = v.x; wtile[il][c4 + 1] = v.y;
      wtile[il][c4 + 2] = v.z; wtile[il][c4 + 3] = v.w;
    }
    __syncthreads();
    unsigned short* out = Wt + ((size_t)((e * 8 + jt) * 32 + kk)) * 4096;
#pragma unroll
    for (int h = 0; h < 2; ++h) {
      const int n   = h * 64 + (t >> 2);
      const int il0 = (t & 3) * 8;
      unsigned u[4];
#pragma unroll
      for (int q = 0; q < 4; ++q)
        u[q] = pack2_bf16(wtile[il0 + 2 * q][n], wtile[il0 + 2 * q + 1][n]);
      *(uint4*)(out + (size_t)(h * 256 + t) * 8) = *(uint4*)u;
    }
  }
}

// ---------------------------------------------------------------------------
// moe_gemm v2: 256x256 tile, BK=32, 8 waves, 4-deep LDS ring, counted
// vmcnt(8), now split into TWO phases per K-tile (T3 per-phase interleave:
// ds_reads + 2 gloads -> barrier -> setprio + 16 MFMA -> barrier). Same MFMA
// sequence/order per accumulator as v1 => bit-identical numerics.
// A staged from row-major Xg via per-lane source addrs; B from chunked Wt.
// GRID MUST BE 512.
__global__ __launch_bounds__(512, 2) void moe_gemm(const unsigned short* __restrict__ Xg,
                                                   const unsigned short* __restrict__ Wt,
                                                   float* __restrict__ Y) {
  __shared__ __align__(16) unsigned short As[4 * 8192];   // 4 bufs x 16 KB
  __shared__ __align__(16) unsigned short Bs[4 * 8192];   // 4 bufs x 16 KB

  const int bid   = blockIdx.x;                 // 512 blocks
  const int lg    = (bid & 7) * 64 + (bid >> 3);
  const int e     = lg >> 5;
  const int inner = lg & 31;
  const int b     = inner >> 3;
  const int mt    = (inner >> 2) & 1;
  const int nt    = inner & 3;

  const int t = threadIdx.x;
  const int w = t >> 6;
  const int l = t & 63;
  const int lrow = l & 15;
  const int q    = l >> 4;

  const int tt0 = b * 64 + e * 4 + mt * 2;      // first 128-row tile of A
  const int jg0 = e * 8 + nt * 2;               // first 128-col Wt group

  const int sr = t >> 2, sc = t & 3;
  const int scs = (sc ^ ((sr >> 1) & 3)) << 3;  // swizzled element offset

  const unsigned short* aC = Xg + ((size_t)(tt0 * 128 + sr)) * (size_t)Ic + scs;
  const size_t lsrc = (size_t)sr * 32 + scs;
  const unsigned short* bC = Wt + (size_t)jg0 * 32 * 4096 + lsrc;

  unsigned short* aL = As + w * 512;            // wave-uniform dest; HW adds lane*16B
  unsigned short* bL = Bs + w * 512;

  auto stageA = [&](int k3) {
    const int bu = (k3 & 3) * 8192;
#pragma unroll
    for (int p = 0; p < 2; ++p)
      async_load16(aC + (size_t)p * 128 * Ic + k3 * 32, aL + bu + p * 4096);
  };
  auto stageB = [&](int k3) {
    const int bu = (k3 & 3) * 8192;
#pragma unroll
    for (int p = 0; p < 2; ++p)
      async_load16(bC + ((size_t)(p * 32 + k3)) * 4096, bL + bu + p * 4096);
  };

  floatx4 acc[8][4];
#pragma unroll
  for (int tm = 0; tm < 8; ++tm)
#pragma unroll
    for (int tn = 0; tn < 4; ++tn) acc[tm][tn] = (floatx4){0.f, 0.f, 0.f, 0.f};

  const int pos = (q ^ ((lrow >> 1) & 3)) << 3;
  const unsigned short* Ard = As + ((w >> 2) << 12) + lrow * 32 + pos;
  const unsigned short* Brd = Bs + (((w >> 1) & 1) << 12) + ((w & 1) * 64 + lrow) * 32 + pos;

#define WAITVM(n) asm volatile("s_waitcnt vmcnt(" #n ")" ::: "memory")
#define CFENCE    asm volatile("" ::: "memory")
#define SBAR      __builtin_amdgcn_s_barrier()
#define SCHED0    __builtin_amdgcn_sched_barrier(0)

  // prime 3 tiles (12 loads in flight), then ensure tile 0 landed
  stageA(0); stageB(0); stageA(1); stageB(1); stageA(2); stageB(2);
  WAITVM(8);
  CFENCE; SBAR; SCHED0;

  // Per tile: phase A {read bf[4]+af[0..3], stage A(kt+3), bar, 16 MFMA, bar}
  //           phase B {read af[4..7], stage B(kt+3), WAITVM, bar, 16 MFMA, bar}
  // WAITVM(8) in phase B guarantees tile kt+1 landed before next iteration.
#define TILE(kt, DO_STAGE, WVM)                                                \
  {                                                                            \
    const int bu = ((kt) & 3) * 8192;                                          \
    short8 bf[4], af[4];                                                       \
    _Pragma("unroll") for (int tn = 0; tn < 4; ++tn)                           \
        bf[tn] = *(const short8*)(Brd + bu + tn * 512);                        \
    _Pragma("unroll") for (int i = 0; i < 4; ++i)                              \
        af[i] = *(const short8*)(Ard + bu + i * 512);                          \
    if (DO_STAGE) stageA((kt) + 3);                                            \
    CFENCE; SBAR; SCHED0;                                                      \
    __builtin_amdgcn_s_setprio(1);                                             \
    _Pragma("unroll") for (int i = 0; i < 4; ++i)                              \
      _Pragma("unroll") for (int tn = 0; tn < 4; ++tn)                         \
          acc[i][tn] =                                                         \
              __builtin_amdgcn_mfma_f32_16x16x32_bf16(af[i], bf[tn],           \
                                                      acc[i][tn], 0, 0, 0);    \
    __builtin_amdgcn_s_setprio(0);                                             \
    SCHED0; CFENCE; SBAR;                                                      \
    _Pragma("unroll") for (int i = 0; i < 4; ++i)                              \
        af[i] = *(const short8*)(Ard + bu + (4 + i) * 512);                    \
    if (DO_STAGE) stageB((kt) + 3);                                            \
    WVM;                                                                       \
    CFENCE; SBAR; SCHED0;                                                      \
    __builtin_amdgcn_s_setprio(1);                                             \
    _Pragma("unroll") for (int i = 0; i < 4; ++i)                              \
      _Pragma("unroll") for (int tn = 0; tn < 4; ++tn)                         \
          acc[4 + i][tn] =                                                     \
              __builtin_amdgcn_mfma_f32_16x16x32_bf16(af[i], bf[tn],           \
                                                      acc[4 + i][tn], 0, 0, 0);\
    __builtin_amdgcn_s_setprio(0);                                             \
    SCHED0; CFENCE; SBAR; SCHED0;                                              \
  }

#pragma unroll 4
  for (int kt = 0; kt < 28; ++kt) TILE(kt, true, WAITVM(8));
  TILE(28, true, WAITVM(8));     // stages tile 31
  TILE(29, false, WAITVM(4));    // drains tile 30
  TILE(30, false, WAITVM(0));    // drains tile 31
  TILE(31, false, (void)0);

  // epilogue: C/D layout col = lane&15, row = quad*4 + reg
  float* Yp = Y + (((size_t)(b * Ec + e) * Kc + (size_t)mt * 256) * Jc) + nt * 256;
  const int wmRow = (w >> 2) * 128;
  const int wnCol = (w & 3) * 64;
#pragma unroll
  for (int tm = 0; tm < 8; ++tm) {
#pragma unroll
    for (int tn = 0; tn < 4; ++tn) {
#pragma unroll
      for (int r = 0; r < 4; ++r) {
        const int row = wmRow + tm * 16 + q * 4 + r;
        const int col = wnCol + tn * 16 + lrow;
        Yp[(size_t)row * Jc + col] = acc[tm][tn][r];
      }
    }
  }
}

extern "C" void kernel_launch(void* const* d_in, const int* in_sizes, int n_in,
                              void* d_out, int out_size, void* d_ws, size_t ws_size,
                              hipStream_t stream) {
  const float* X = (const float*)d_in[0];
  const int* ind = (const int*)d_in[1];
  const float* W = (const float*)d_in[2];
  float* Y = (float*)d_out;

  unsigned short* Xg = (unsigned short*)d_ws;                              // 64 MiB, row-major [32768][1024]
  unsigned short* Wt = (unsigned short*)d_ws + (size_t)Bc * Ec * Kc * Ic;  // 32 MiB, chunked

  hipLaunchKernelGGL(prep, dim3(8192), dim3(256), 0, stream, X, ind, W, Xg, Wt);
  // moe_gemm decomposes blockIdx assuming exactly 512 blocks (8-XCD chunked).
  hipLaunchKernelGGL(moe_gemm, dim3(512), dim3(512), 0, stream, Xg, Wt, Y);
}